// Round 1
// baseline (6233.285 us; speedup 1.0000x reference)
//
#include <hip/hip_runtime.h>

typedef _Float16 half8 __attribute__((ext_vector_type(8)));
typedef float floatx4 __attribute__((ext_vector_type(4)));
typedef unsigned int u32;
typedef unsigned long long u64;

#define T_SEQ 4096
#define EMBD  512
#define HID   1024
#define G4    4096   /* 4*HID */
#define NWG   64     /* recurrence workgroups */

/* ---------------- helpers ---------------- */

__device__ __forceinline__ void stage16(const void* g, void* l) {
  __builtin_amdgcn_global_load_lds((const __attribute__((address_space(1))) u32*)g,
                                   (__attribute__((address_space(3))) u32*)l, 16, 0, 0);
}

__device__ __forceinline__ float fsigmoid(float x) {
  return 1.f / (1.f + __expf(-x));
}
__device__ __forceinline__ float ftanh(float x) {
  x = fminf(fmaxf(x, -15.f), 15.f);
  float e = __expf(2.f * x);
  return (e - 1.f) / (e + 1.f);
}

/* ---------------- phase 0: convert / gather / init ---------------- */

__global__ __launch_bounds__(256) void prep_kernel(
    const float* __restrict__ Whh, const float* __restrict__ Wih,
    const float* __restrict__ emb, const int* __restrict__ words,
    const float* __restrict__ bih, const float* __restrict__ bhh,
    _Float16* __restrict__ whh_h, _Float16* __restrict__ wih_h,
    _Float16* __restrict__ xh, float* __restrict__ biasf, u64* __restrict__ hg) {
  const long long S1 = (long long)G4 * HID;   // 4194304
  const long long S2 = (long long)G4 * EMBD;  // 2097152
  const long long S3 = (long long)T_SEQ * EMBD; // 2097152
  const long long S4 = G4;
  const long long S5 = 2048;
  const long long tot = S1 + S2 + S3 + S4 + S5;
  long long stride = (long long)gridDim.x * blockDim.x;
  for (long long i = (long long)blockIdx.x * blockDim.x + threadIdx.x; i < tot; i += stride) {
    long long j = i;
    if (j < S1) { whh_h[j] = (_Float16)Whh[j]; continue; }
    j -= S1;
    if (j < S2) { wih_h[j] = (_Float16)Wih[j]; continue; }
    j -= S2;
    if (j < S3) {
      int t = (int)(j >> 9), e = (int)(j & 511);
      xh[j] = (_Float16)emb[(long long)words[t] * EMBD + e];
      continue;
    }
    j -= S3;
    if (j < S4) { biasf[j] = bih[j] + bhh[j]; continue; }
    j -= S4;
    hg[j] = 0ull;
  }
}

/* ---------------- phase 1: xg = x @ Wih^T + bias, column-permuted ----------
   A = xh [T,512] fp16 row-major, B^T = wih_h [4096,512] fp16 row-major.
   C written as xg_p[t][w*64 + g*16 + jj] for source col n = g*1024 + w*16 + jj. */

__global__ __launch_bounds__(256) void xg_gemm(
    const _Float16* __restrict__ A, const _Float16* __restrict__ B,
    const float* __restrict__ biasf, float* __restrict__ C) {
  __shared__ char smem[2][2][8192];
  const int tid = threadIdx.x;
  const int lane = tid & 63;
  const int wid = tid >> 6;
  const int wy = wid >> 1, wx = wid & 1;
  const int tm = blockIdx.x * 128, tn = blockIdx.y * 128;

  floatx4 acc[4][4];
#pragma unroll
  for (int a = 0; a < 4; a++)
#pragma unroll
    for (int b = 0; b < 4; b++) acc[a][b] = (floatx4){0.f, 0.f, 0.f, 0.f};

  auto stage = [&](int buf, int kb) {
#pragma unroll
    for (int ii = 0; ii < 2; ii++) {
      int ci = tid + ii * 256;        // 0..511 chunks of 16B
      int r = ci >> 2, cs = ci & 3;
      int c = cs ^ (r & 3);           // inverse-swizzled source slot
      const _Float16* srcA = A + (long long)(tm + r) * EMBD + kb + c * 8;
      const _Float16* srcB = B + (long long)(tn + r) * EMBD + kb + c * 8;
      char* ldsA = &smem[buf][0][(ci & ~63) << 4];   // wave-uniform base
      char* ldsB = &smem[buf][1][(ci & ~63) << 4];
      stage16(srcA, ldsA);
      stage16(srcB, ldsB);
    }
  };

  stage(0, 0);
  __syncthreads();

  for (int t = 0; t < 16; t++) {
    int cur = t & 1;
    if (t < 15) stage(cur ^ 1, (t + 1) * 32);   // async, in flight during compute
    const char* As = smem[cur][0];
    const char* Bs = smem[cur][1];
    const int kc = lane >> 4;
    half8 af[4], bfr[4];
#pragma unroll
    for (int am = 0; am < 4; am++) {
      int r = wy * 64 + am * 16 + (lane & 15);
      af[am] = *(const half8*)(As + r * 64 + ((kc ^ (r & 3)) << 4));
    }
#pragma unroll
    for (int bn = 0; bn < 4; bn++) {
      int r = wx * 64 + bn * 16 + (lane & 15);
      bfr[bn] = *(const half8*)(Bs + r * 64 + ((kc ^ (r & 3)) << 4));
    }
#pragma unroll
    for (int am = 0; am < 4; am++)
#pragma unroll
      for (int bn = 0; bn < 4; bn++)
        acc[am][bn] = __builtin_amdgcn_mfma_f32_16x16x32_f16(af[am], bfr[bn], acc[am][bn], 0, 0, 0);
    __syncthreads();   // drains in-flight next-tile loads (vmcnt) + protects buffers
  }

#pragma unroll
  for (int am = 0; am < 4; am++) {
    int mrow = tm + wy * 64 + am * 16 + (lane >> 4) * 4;
#pragma unroll
    for (int bn = 0; bn < 4; bn++) {
      int n = tn + wx * 64 + bn * 16 + (lane & 15);
      int w = (n & 1023) >> 4, g = n >> 10, jj = n & 15;
      int np = w * 64 + g * 16 + jj;
      float bias = biasf[n];
#pragma unroll
      for (int rg = 0; rg < 4; rg++)
        C[(long long)(mrow + rg) * G4 + np] = acc[am][bn][rg] + bias;
    }
  }
}

/* ---------------- phase 2: persistent forward LSTM recurrence ----------------
   64 WGs x 512 threads. WG wg owns h[wg*16 .. wg*16+16).
   Wave w: gate rt = w&3, k-half kh = w>>2. Whh fragments resident in VGPRs.
   h broadcast via self-tagged u64 atomics (agent scope), double-buffered by parity. */

__global__ __launch_bounds__(512) void lstm_fwd(
    const _Float16* __restrict__ Whh_h, const float* __restrict__ xg,
    u64* __restrict__ hg) {
  __shared__ u32 hp[512];       // 1024 packed fp16 h values
  __shared__ float part[128];   // 8 waves x 16 partial dots
  const int tid = threadIdx.x;
  const int lane = tid & 63;
  const int w = tid >> 6;
  const int rt = w & 3;
  const int kh = w >> 2;
  const int wg = blockIdx.x;

  // load persistent weight fragments: B[k][n] = Whh[rt*1024 + wg*16 + n][k]
  half8 Wb[16];
  {
    const int n = lane & 15, kc = lane >> 4;
    const _Float16* wr = Whh_h + (long long)(rt * HID + wg * 16 + n) * HID + kh * 512;
#pragma unroll
    for (int kk = 0; kk < 16; kk++)
      Wb[kk] = *(const half8*)(wr + kk * 32 + kc * 8);
  }

  u64* h0 = hg;
  u64* h1 = hg + 1024;
  float c = 0.f;

  for (int s = 0; s < T_SEQ; s++) {
    u64* src = (s & 1) ? h1 : h0;
    u64* dst = (s & 1) ? h0 : h1;

    // prefetch this step's xg slice (gate biases for our 16 h-elements)
    float xa = 0.f, xb = 0.f, xc = 0.f, xd = 0.f;
    if (tid < 16) {
      const float* xr = xg + (long long)s * G4 + wg * 64;
      xa = xr[tid]; xb = xr[16 + tid]; xc = xr[32 + tid]; xd = xr[48 + tid];
    }

    // poll + stage h into LDS as fp16
    {
      const int e = tid * 2;
      const u32 want = (u32)s;
      u64 v0 = 0, v1 = 0;
      bool d0 = false, d1 = false;
      do {
        if (!d0) { v0 = __hip_atomic_load(&src[e],     __ATOMIC_RELAXED, __HIP_MEMORY_SCOPE_AGENT); d0 = ((u32)(v0 >> 32) == want); }
        if (!d1) { v1 = __hip_atomic_load(&src[e + 1], __ATOMIC_RELAXED, __HIP_MEMORY_SCOPE_AGENT); d1 = ((u32)(v1 >> 32) == want); }
      } while (!(d0 && d1));
      union { _Float16 h[2]; u32 u; } pk;
      pk.h[0] = (_Float16)__uint_as_float((u32)v0);
      pk.h[1] = (_Float16)__uint_as_float((u32)v1);
      hp[tid] = pk.u;
    }
    __syncthreads();

    // matvec via MFMA: A = h replicated over 16 rows (only row 0 of C is read)
    {
      const char* hh = (const char*)hp;
      const int kc = lane >> 4;
      floatx4 a0 = (floatx4){0.f, 0.f, 0.f, 0.f};
      floatx4 a1 = (floatx4){0.f, 0.f, 0.f, 0.f};
#pragma unroll
      for (int kk = 0; kk < 16; kk += 2) {
        half8 av0 = *(const half8*)(hh + (kh * 512 + kk * 32 + kc * 8) * 2);
        a0 = __builtin_amdgcn_mfma_f32_16x16x32_f16(av0, Wb[kk], a0, 0, 0, 0);
        half8 av1 = *(const half8*)(hh + (kh * 512 + (kk + 1) * 32 + kc * 8) * 2);
        a1 = __builtin_amdgcn_mfma_f32_16x16x32_f16(av1, Wb[kk + 1], a1, 0, 0, 0);
      }
      if (lane < 16) part[w * 16 + lane] = a0[0] + a1[0];
    }
    __syncthreads();

    // activation + publish new h (threads 0..15 own h[wg*16+tid])
    if (tid < 16) {
      float gi = xa + part[0  + tid] + part[64 + 0  + tid];
      float gf = xb + part[16 + tid] + part[64 + 16 + tid];
      float gg = xc + part[32 + tid] + part[64 + 32 + tid];
      float go = xd + part[48 + tid] + part[64 + 48 + tid];
      float i_ = fsigmoid(gi);
      float f_ = fsigmoid(gf);
      float g_ = ftanh(gg);
      float o_ = fsigmoid(go);
      c = f_ * c + i_ * g_;
      float hn = o_ * ftanh(c);
      u64 pkv = ((u64)(u32)(s + 1) << 32) | (u64)__float_as_uint(hn);
      __hip_atomic_store(&dst[wg * 16 + tid], pkv, __ATOMIC_RELAXED, __HIP_MEMORY_SCOPE_AGENT);
    }
    // no trailing barrier needed: next step's poll gates all cross-wave reuse
  }
}

/* ---------------- phase 3: backward direction = ONE cell step on x[T-1] ------- */

__global__ __launch_bounds__(256) void bwd_gates(
    const float* __restrict__ Wihb, const float* __restrict__ emb,
    const int* __restrict__ words, const float* __restrict__ bihb,
    const float* __restrict__ bhhb, float* __restrict__ gb) {
  const int row = blockIdx.x * 4 + (threadIdx.x >> 6);
  const int lane = threadIdx.x & 63;
  const long long wl = words[T_SEQ - 1];
  const float* xr = emb + wl * EMBD;
  const float* wr = Wihb + (long long)row * EMBD;
  const int k0 = lane * 8;
  float s = 0.f;
#pragma unroll
  for (int j = 0; j < 8; j += 4) {
    float4 wv = *(const float4*)(wr + k0 + j);
    float4 xv = *(const float4*)(xr + k0 + j);
    s += wv.x * xv.x + wv.y * xv.y + wv.z * xv.z + wv.w * xv.w;
  }
#pragma unroll
  for (int m = 1; m < 64; m <<= 1) s += __shfl_xor(s, m);
  if (lane == 0) gb[row] = s + bihb[row] + bhhb[row];
}

/* ---------------- phase 4: backward activations + projection ---------------- */

__global__ __launch_bounds__(256) void final_k(
    const u64* __restrict__ hg, const float* __restrict__ gb,
    const float* __restrict__ Wp, const float* __restrict__ bp,
    float* __restrict__ out) {
  __shared__ float last[2 * HID];
  __shared__ float red[4];
  const int tid = threadIdx.x;
  for (int j = tid; j < HID; j += 256) {
    last[j] = __uint_as_float((u32)hg[j]);          // h_T sits in parity-0 buffer
    float i_ = fsigmoid(gb[j]);
    float g_ = ftanh(gb[2 * HID + j]);
    float o_ = fsigmoid(gb[3 * HID + j]);
    float cb = i_ * g_;                              // c0 = 0, so f-gate irrelevant
    last[HID + j] = o_ * ftanh(cb);
  }
  __syncthreads();
  const int lane = tid & 63, wv = tid >> 6;
  for (int n = 0; n < 5; n++) {
    float p = 0.f;
    for (int j = tid; j < 2 * HID; j += 256) p += last[j] * Wp[n * 2 * HID + j];
#pragma unroll
    for (int m = 1; m < 64; m <<= 1) p += __shfl_xor(p, m);
    if (lane == 0) red[wv] = p;
    __syncthreads();
    if (tid == 0) out[n] = red[0] + red[1] + red[2] + red[3] + bp[n];
    __syncthreads();
  }
}

/* ---------------- launcher ---------------- */

extern "C" void kernel_launch(void* const* d_in, const int* in_sizes, int n_in,
                              void* d_out, int out_size, void* d_ws, size_t ws_size,
                              hipStream_t stream) {
  const int*   words = (const int*)d_in[0];
  const float* emb   = (const float*)d_in[1];
  const float* Wih_f = (const float*)d_in[2];
  const float* Whh_f = (const float*)d_in[3];
  const float* bih_f = (const float*)d_in[4];
  const float* bhh_f = (const float*)d_in[5];
  const float* Wih_b = (const float*)d_in[6];
  /* d_in[7] = Whh_b: unused — backward direction is a single step from zero state */
  const float* bih_b = (const float*)d_in[8];
  const float* bhh_b = (const float*)d_in[9];
  const float* Wp    = (const float*)d_in[10];
  const float* bp    = (const float*)d_in[11];
  float* out = (float*)d_out;

  char* ws = (char*)d_ws;
  float*    XG    = (float*)(ws);                    // [T,4H] f32, col-permuted: 64 MB
  _Float16* WHH   = (_Float16*)(ws + 67108864);      // [4H,H] fp16: 8 MB
  _Float16* WIH   = (_Float16*)(ws + 75497472);      // [4H,E] fp16: 4 MB
  _Float16* XH    = (_Float16*)(ws + 79691776);      // [T,E]  fp16: 4 MB
  u64*      HG    = (u64*)(ws + 83886080);           // 2 x 1024 tagged h: 16 KB
  float*    GB    = (float*)(ws + 83902464);         // backward gates: 16 KB
  float*    BIASF = (float*)(ws + 83918848);         // bih_f + bhh_f: 16 KB

  prep_kernel<<<2048, 256, 0, stream>>>(Whh_f, Wih_f, emb, words, bih_f, bhh_f,
                                        WHH, WIH, XH, BIASF, HG);
  xg_gemm<<<dim3(32, 32), 256, 0, stream>>>(XH, WIH, BIASF, XG);
  lstm_fwd<<<NWG, 512, 0, stream>>>(WHH, XG, HG);
  bwd_gates<<<1024, 256, 0, stream>>>(Wih_b, emb, words, bih_b, bhh_b, GB);
  final_k<<<1, 256, 0, stream>>>(HG, GB, Wp, bp, out);
}